// Round 3
// baseline (341.179 us; speedup 1.0000x reference)
//
#include <hip/hip_runtime.h>
#include <hip/hip_bf16.h>
#include <stdint.h>

typedef __attribute__((ext_vector_type(8))) short short8;
typedef __attribute__((ext_vector_type(4))) float f32x4;

__device__ __forceinline__ short f2bf(float f) {
  union { float f; unsigned u; } x; x.f = f;
  unsigned r = (x.u + 0x7FFFu + ((x.u >> 16) & 1u)) >> 16;
  return (short)r;
}
__device__ __forceinline__ float bf2f(short s) {
  union { unsigned u; float f; } x; x.u = ((unsigned)(unsigned short)s) << 16;
  return x.f;
}
__device__ __forceinline__ short8 cvt8(const float* p) {
  const float4 f0 = *(const float4*)p;
  const float4 f1 = *(const float4*)(p + 4);
  short8 r;
  r[0] = f2bf(f0.x); r[1] = f2bf(f0.y); r[2] = f2bf(f0.z); r[3] = f2bf(f0.w);
  r[4] = f2bf(f1.x); r[5] = f2bf(f1.y); r[6] = f2bf(f1.z); r[7] = f2bf(f1.w);
  return r;
}

// packed weights in d_ws (bf16 bit patterns in shorts):
//   pWin : [3][8ks][8nf][64lane][8]   elems     0 .. 98303
//   pWh  : [3][2][4ks][8nf][64][8]    elems  98304 .. 196607
//   pWout: [3][4ks][16nf][64][8]      elems 196608 .. 294911
__global__ __launch_bounds__(256) void pack_weights(
    const float* __restrict__ Win, const float* __restrict__ Wh,
    const float* __restrict__ Wout, short* __restrict__ o) {
  int gid = blockIdx.x * 256 + threadIdx.x;
  if (gid < 12288) {
    int t = gid / 4096, r = gid % 4096;
    int ks = r / 512, r2 = r % 512, nf = r2 / 64, l = r2 % 64;
    int n = nf * 16 + (l & 15);
    int kb = ks * 32 + (l >> 4) * 8;
#pragma unroll
    for (int i = 0; i < 8; ++i)
      o[gid * 8 + i] = f2bf(Win[(t * 256 + kb + i) * 128 + n]);
  } else if (gid < 24576) {
    int h = gid - 12288;
    int tl = h / 2048, r = h % 2048;
    int ks = r / 512, nf = (r % 512) / 64, l = r % 64;
    int n = nf * 16 + (l & 15);
    int kb = ks * 32 + (l >> 4) * 8;
#pragma unroll
    for (int i = 0; i < 8; ++i)
      o[98304 + h * 8 + i] = f2bf(Wh[(tl * 128 + kb + i) * 128 + n]);
  } else {
    int oo = gid - 24576;
    int t = oo / 4096, r = oo % 4096;
    int ks = r / 1024, nf = (r % 1024) / 64, l = r % 64;
    int n = nf * 16 + (l & 15);
    int kb = ks * 32 + (l >> 4) * 8;
#pragma unroll
    for (int i = 0; i < 8; ++i)
      o[196608 + oo * 8 + i] = f2bf(Wout[(t * 128 + kb + i) * 256 + n]);
  }
}

__global__ __launch_bounds__(256, 4) void fused_towers(
    const int* __restrict__ user, const int* __restrict__ item,
    const float* __restrict__ su, const float* __restrict__ ti,
    const float* __restrict__ bin, const float* __restrict__ bh,
    const float* __restrict__ bout, const short* __restrict__ wp,
    float* __restrict__ out) {
  // Act: during layers = Ha[16KB] + Hb[16KB] (rows of 256B, XOR-swizzled);
  // during tail = x tile, 64 rows x 512B (XOR-swizzled).
  __shared__ __align__(16) char Act[32768];
  __shared__ float sL[3][64];
  __shared__ float sS[3][64];
  __shared__ int sUid[64];
  __shared__ int sItm[64];

  const int tid = threadIdx.x;
  const int w = tid >> 6, lane = tid & 63;
  const int ar = lane & 15, g = lane >> 4;
  const f32x4 fz = {0.f, 0.f, 0.f, 0.f};

  if (tid < 64) {
    sUid[tid] = user[blockIdx.x * 64 + tid];
    sItm[tid] = item[blockIdx.x * 64 + tid];
  }
  __syncthreads();

  char* const Ha = Act;
  char* const Hb = Act + 16384;

  for (int t = 0; t < 3; ++t) {
    // ---------- L1: [64x256] @ [256x128] -> Ha (relu + bin) ----------
    f32x4 acc2[4][2];
#pragma unroll
    for (int m = 0; m < 4; ++m) { acc2[m][0] = fz; acc2[m][1] = fz; }
    const float* up[4];
#pragma unroll
    for (int m = 0; m < 4; ++m) up[m] = su + (size_t)sUid[m * 16 + ar] * 256;
#pragma unroll
    for (int K0 = 0; K0 < 8; ++K0) {
      short8 a[4];
#pragma unroll
      for (int m = 0; m < 4; ++m) a[m] = cvt8(up[m] + K0 * 32 + g * 8);
#pragma unroll
      for (int nfl = 0; nfl < 2; ++nfl) {
        const short8 b = *(const short8*)(wp + (size_t)((t * 8 + K0) * 8 + w * 2 + nfl) * 512 + lane * 8);
#pragma unroll
        for (int m = 0; m < 4; ++m)
          acc2[m][nfl] = __builtin_amdgcn_mfma_f32_16x16x32_bf16(a[m], b, acc2[m][nfl], 0, 0, 0);
      }
    }
#pragma unroll
    for (int m = 0; m < 4; ++m)
#pragma unroll
      for (int nfl = 0; nfl < 2; ++nfl) {
        const int col = w * 32 + nfl * 16 + ar;
        const float bv = bin[t * 128 + col];
#pragma unroll
        for (int q = 0; q < 4; ++q) {
          const int r = m * 16 + g * 4 + q;
          const float v = fmaxf(acc2[m][nfl][q] + bv, 0.f);
          *(short*)(Ha + r * 256 + ((col * 2) ^ ((r & 7) << 4))) = f2bf(v);
        }
      }
    __syncthreads();

    // ---------- L2, L3: [64x128] @ [128x128] ----------
#pragma unroll
    for (int L = 0; L < 2; ++L) {
      char* const hin = L ? Hb : Ha;
      char* const hout = L ? Ha : Hb;
#pragma unroll
      for (int m = 0; m < 4; ++m) { acc2[m][0] = fz; acc2[m][1] = fz; }
#pragma unroll
      for (int ks = 0; ks < 4; ++ks) {
        short8 a[4];
#pragma unroll
        for (int m = 0; m < 4; ++m) {
          const int r = m * 16 + ar;
          a[m] = *(const short8*)(hin + r * 256 + ((ks * 64 + g * 16) ^ ((r & 7) << 4)));
        }
#pragma unroll
        for (int nfl = 0; nfl < 2; ++nfl) {
          const short8 b = *(const short8*)(wp + 98304 + (size_t)(((t * 2 + L) * 4 + ks) * 8 + w * 2 + nfl) * 512 + lane * 8);
#pragma unroll
          for (int m = 0; m < 4; ++m)
            acc2[m][nfl] = __builtin_amdgcn_mfma_f32_16x16x32_bf16(a[m], b, acc2[m][nfl], 0, 0, 0);
        }
      }
#pragma unroll
      for (int m = 0; m < 4; ++m)
#pragma unroll
        for (int nfl = 0; nfl < 2; ++nfl) {
          const int col = w * 32 + nfl * 16 + ar;
          const float bv = bh[(t * 2 + L) * 128 + col];
#pragma unroll
          for (int q = 0; q < 4; ++q) {
            const int r = m * 16 + g * 4 + q;
            const float v = fmaxf(acc2[m][nfl][q] + bv, 0.f);
            *(short*)(hout + r * 256 + ((col * 2) ^ ((r & 7) << 4))) = f2bf(v);
          }
        }
      __syncthreads();
    }

    // ---------- L4: [64x128] @ [128x256] ----------
    f32x4 acc4[4][4];
#pragma unroll
    for (int m = 0; m < 4; ++m)
#pragma unroll
      for (int n = 0; n < 4; ++n) acc4[m][n] = fz;
#pragma unroll
    for (int K0 = 0; K0 < 4; ++K0) {
      short8 a[4];
#pragma unroll
      for (int m = 0; m < 4; ++m) {
        const int r = m * 16 + ar;
        a[m] = *(const short8*)(Ha + r * 256 + ((K0 * 64 + g * 16) ^ ((r & 7) << 4)));
      }
#pragma unroll
      for (int nfl = 0; nfl < 4; ++nfl) {
        const short8 b = *(const short8*)(wp + 196608 + (size_t)((t * 4 + K0) * 16 + w * 4 + nfl) * 512 + lane * 8);
#pragma unroll
        for (int m = 0; m < 4; ++m)
          acc4[m][nfl] = __builtin_amdgcn_mfma_f32_16x16x32_bf16(a[m], b, acc4[m][nfl], 0, 0, 0);
      }
    }
    __syncthreads();  // all Ha reads done before Act is overwritten with x

    // write x = acc4 + bout into Act as bf16, row r at r*512B, swizzled
#pragma unroll
    for (int m = 0; m < 4; ++m)
#pragma unroll
      for (int nfl = 0; nfl < 4; ++nfl) {
        const int col = w * 64 + nfl * 16 + ar;
        const float bo = bout[t * 256 + col];
#pragma unroll
        for (int q = 0; q < 4; ++q) {
          const int r = m * 16 + g * 4 + q;
          *(short*)(Act + r * 512 + ((col * 2) ^ ((r & 7) << 4))) = f2bf(acc4[m][nfl][q] + bo);
        }
      }
    __syncthreads();

    // ---------- tail: 4 lanes per row, vectorized dots ----------
    {
      const int rr = tid >> 2, qq = tid & 3;
      const float* kv = ti + (size_t)sUid[rr] * 256 + qq * 64;
      const float* ev = ti + (size_t)sItm[rr] * 256 + qq * 64;
      float l = 0.f, s = 0.f;
#pragma unroll
      for (int i = 0; i < 8; ++i) {
        const short8 xv = *(const short8*)(Act + rr * 512 + ((qq * 128 + i * 16) ^ ((rr & 7) << 4)));
        const float4 ka = *(const float4*)(kv + i * 8);
        const float4 kb = *(const float4*)(kv + i * 8 + 4);
        const float4 ea = *(const float4*)(ev + i * 8);
        const float4 eb = *(const float4*)(ev + i * 8 + 4);
        const float x0 = bf2f(xv[0]), x1 = bf2f(xv[1]), x2 = bf2f(xv[2]), x3 = bf2f(xv[3]);
        const float x4 = bf2f(xv[4]), x5 = bf2f(xv[5]), x6 = bf2f(xv[6]), x7 = bf2f(xv[7]);
        l += x0 * ka.x + x1 * ka.y + x2 * ka.z + x3 * ka.w
           + x4 * kb.x + x5 * kb.y + x6 * kb.z + x7 * kb.w;
        s += x0 * ea.x + x1 * ea.y + x2 * ea.z + x3 * ea.w
           + x4 * eb.x + x5 * eb.y + x6 * eb.z + x7 * eb.w;
      }
      l += __shfl_xor(l, 1); l += __shfl_xor(l, 2);
      s += __shfl_xor(s, 1); s += __shfl_xor(s, 2);
      if (qq == 0) { sL[t][rr] = l; sS[t][rr] = s; }
    }
    __syncthreads();
  }

  if (tid < 64) {
    const float l0 = sL[0][tid], l1 = sL[1][tid], l2 = sL[2][tid];
    const float mx = fmaxf(l0, fmaxf(l1, l2));
    const float e0 = __expf(l0 - mx), e1 = __expf(l1 - mx), e2 = __expf(l2 - mx);
    out[blockIdx.x * 64 + tid] =
        (e0 * sS[0][tid] + e1 * sS[1][tid] + e2 * sS[2][tid]) / (e0 + e1 + e2);
  }
}

extern "C" void kernel_launch(void* const* d_in, const int* in_sizes, int n_in,
                              void* d_out, int out_size, void* d_ws, size_t ws_size,
                              hipStream_t stream) {
  const int* user = (const int*)d_in[0];
  const int* item = (const int*)d_in[1];
  const float* su = (const float*)d_in[2];
  const float* ti = (const float*)d_in[3];
  const float* Win = (const float*)d_in[4];
  const float* bin = (const float*)d_in[5];
  const float* Wh = (const float*)d_in[6];
  const float* bh = (const float*)d_in[7];
  const float* Wout = (const float*)d_in[8];
  const float* bout = (const float*)d_in[9];
  float* out = (float*)d_out;
  short* ws = (short*)d_ws;

  hipLaunchKernelGGL(pack_weights, dim3(144), dim3(256), 0, stream, Win, Wh, Wout, ws);
  hipLaunchKernelGGL(fused_towers, dim3(1024), dim3(256), 0, stream,
                     user, item, su, ti, bin, bh, bout, (const short*)ws, out);
}

// Round 4
// 281.275 us; speedup vs baseline: 1.2130x; 1.2130x over previous
//
#include <hip/hip_runtime.h>
#include <hip/hip_bf16.h>
#include <stdint.h>

typedef __attribute__((ext_vector_type(8))) short short8;
typedef __attribute__((ext_vector_type(4))) float f32x4;

__device__ __forceinline__ short f2bf(float f) {
  __hip_bfloat16 h = __float2bfloat16(f);  // RNE; compiler fuses pairs into v_cvt_pk_bf16_f32
  union { __hip_bfloat16 h; unsigned short u; } c;
  c.h = h;
  return (short)c.u;
}
__device__ __forceinline__ float bf2f(short s) {
  union { unsigned u; float f; } x; x.u = ((unsigned)(unsigned short)s) << 16;
  return x.f;
}
__device__ __forceinline__ short8 cvt8(const float* p) {
  const float4 f0 = *(const float4*)p;
  const float4 f1 = *(const float4*)(p + 4);
  short8 r;
  r[0] = f2bf(f0.x); r[1] = f2bf(f0.y); r[2] = f2bf(f0.z); r[3] = f2bf(f0.w);
  r[4] = f2bf(f1.x); r[5] = f2bf(f1.y); r[6] = f2bf(f1.z); r[7] = f2bf(f1.w);
  return r;
}

// packed weights in d_ws (bf16 bit patterns in shorts):
//   pWin : [3][8ks][8nf][64lane][8]   elems     0 .. 98303
//   pWh  : [3][2][4ks][8nf][64][8]    elems  98304 .. 196607
//   pWout: [3][4ks][16nf][64][8]      elems 196608 .. 294911
__global__ __launch_bounds__(256) void pack_weights(
    const float* __restrict__ Win, const float* __restrict__ Wh,
    const float* __restrict__ Wout, short* __restrict__ o) {
  int gid = blockIdx.x * 256 + threadIdx.x;
  if (gid < 12288) {
    int t = gid / 4096, r = gid % 4096;
    int ks = r / 512, r2 = r % 512, nf = r2 / 64, l = r2 % 64;
    int n = nf * 16 + (l & 15);
    int kb = ks * 32 + (l >> 4) * 8;
#pragma unroll
    for (int i = 0; i < 8; ++i)
      o[gid * 8 + i] = f2bf(Win[(t * 256 + kb + i) * 128 + n]);
  } else if (gid < 24576) {
    int h = gid - 12288;
    int tl = h / 2048, r = h % 2048;
    int ks = r / 512, nf = (r % 512) / 64, l = r % 64;
    int n = nf * 16 + (l & 15);
    int kb = ks * 32 + (l >> 4) * 8;
#pragma unroll
    for (int i = 0; i < 8; ++i)
      o[98304 + h * 8 + i] = f2bf(Wh[(tl * 128 + kb + i) * 128 + n]);
  } else {
    int oo = gid - 24576;
    int t = oo / 4096, r = oo % 4096;
    int ks = r / 1024, nf = (r % 1024) / 64, l = r % 64;
    int n = nf * 16 + (l & 15);
    int kb = ks * 32 + (l >> 4) * 8;
#pragma unroll
    for (int i = 0; i < 8; ++i)
      o[196608 + oo * 8 + i] = f2bf(Wout[(t * 128 + kb + i) * 256 + n]);
  }
}

__global__ __launch_bounds__(256, 3) void fused_towers(
    const int* __restrict__ user, const int* __restrict__ item,
    const float* __restrict__ su, const float* __restrict__ ti,
    const float* __restrict__ bin, const float* __restrict__ bh,
    const float* __restrict__ bout, const short* __restrict__ wp,
    float* __restrict__ out) {
  // Act: layers use Ha[0,16K) + Hb[16K,32K) (rows 256B, XOR-swizzled).
  // Tail: xA (L4 cols w*64+0..31) lives in Hb, xB (cols w*64+32..63) in Ha.
  __shared__ __align__(16) char Act[32768];
  __shared__ float sL[3][64];
  __shared__ float sS[3][64];
  __shared__ int sUid[64];
  __shared__ int sItm[64];

  const int tid = threadIdx.x;
  const int w = tid >> 6, lane = tid & 63;
  const int ar = lane & 15, g = lane >> 4;
  const f32x4 fz = {0.f, 0.f, 0.f, 0.f};

  if (tid < 64) {
    sUid[tid] = user[blockIdx.x * 64 + tid];
    sItm[tid] = item[blockIdx.x * 64 + tid];
  }
  __syncthreads();

  char* const Ha = Act;
  char* const Hb = Act + 16384;

  for (int t = 0; t < 3; ++t) {
    // ---------- L1: [64x256] @ [256x128] -> Ha (relu + bin) ----------
    f32x4 acc[4][2];
#pragma unroll
    for (int m = 0; m < 4; ++m) { acc[m][0] = fz; acc[m][1] = fz; }
    const float* up[4];
#pragma unroll
    for (int m = 0; m < 4; ++m) up[m] = su + (size_t)sUid[m * 16 + ar] * 256;
#pragma unroll
    for (int K0 = 0; K0 < 8; ++K0) {
      short8 a[4];
#pragma unroll
      for (int m = 0; m < 4; ++m) a[m] = cvt8(up[m] + K0 * 32 + g * 8);
#pragma unroll
      for (int nfl = 0; nfl < 2; ++nfl) {
        const short8 b = *(const short8*)(wp + (size_t)((t * 8 + K0) * 8 + w * 2 + nfl) * 512 + lane * 8);
#pragma unroll
        for (int m = 0; m < 4; ++m)
          acc[m][nfl] = __builtin_amdgcn_mfma_f32_16x16x32_bf16(a[m], b, acc[m][nfl], 0, 0, 0);
      }
    }
#pragma unroll
    for (int m = 0; m < 4; ++m)
#pragma unroll
      for (int nfl = 0; nfl < 2; ++nfl) {
        const int col = w * 32 + nfl * 16 + ar;
        const float bv = bin[t * 128 + col];
#pragma unroll
        for (int q = 0; q < 4; ++q) {
          const int r = m * 16 + g * 4 + q;
          const float v = fmaxf(acc[m][nfl][q] + bv, 0.f);
          *(short*)(Ha + r * 256 + ((col * 2) ^ ((r & 7) << 4))) = f2bf(v);
        }
      }
    __syncthreads();

    // ---------- L2, L3: [64x128] @ [128x128] ----------
#pragma unroll
    for (int L = 0; L < 2; ++L) {
      char* const hin = L ? Hb : Ha;
      char* const hout = L ? Ha : Hb;
#pragma unroll
      for (int m = 0; m < 4; ++m) { acc[m][0] = fz; acc[m][1] = fz; }
#pragma unroll
      for (int ks = 0; ks < 4; ++ks) {
        short8 a[4];
#pragma unroll
        for (int m = 0; m < 4; ++m) {
          const int r = m * 16 + ar;
          a[m] = *(const short8*)(hin + r * 256 + ((ks * 64 + g * 16) ^ ((r & 7) << 4)));
        }
#pragma unroll
        for (int nfl = 0; nfl < 2; ++nfl) {
          const short8 b = *(const short8*)(wp + 98304 + (size_t)(((t * 2 + L) * 4 + ks) * 8 + w * 2 + nfl) * 512 + lane * 8);
#pragma unroll
          for (int m = 0; m < 4; ++m)
            acc[m][nfl] = __builtin_amdgcn_mfma_f32_16x16x32_bf16(a[m], b, acc[m][nfl], 0, 0, 0);
        }
      }
#pragma unroll
      for (int m = 0; m < 4; ++m)
#pragma unroll
        for (int nfl = 0; nfl < 2; ++nfl) {
          const int col = w * 32 + nfl * 16 + ar;
          const float bv = bh[(t * 2 + L) * 128 + col];
#pragma unroll
          for (int q = 0; q < 4; ++q) {
            const int r = m * 16 + g * 4 + q;
            const float v = fmaxf(acc[m][nfl][q] + bv, 0.f);
            *(short*)(hout + r * 256 + ((col * 2) ^ ((r & 7) << 4))) = f2bf(v);
          }
        }
      __syncthreads();
    }

    // ---------- L4: [64x128] @ [128x256] in two N-half passes ----------
    // pass 0: cols w*64 + {0..31} -> xA into Hb (dead after L3)
#pragma unroll
    for (int m = 0; m < 4; ++m) { acc[m][0] = fz; acc[m][1] = fz; }
#pragma unroll
    for (int K0 = 0; K0 < 4; ++K0) {
      short8 a[4];
#pragma unroll
      for (int m = 0; m < 4; ++m) {
        const int r = m * 16 + ar;
        a[m] = *(const short8*)(Ha + r * 256 + ((K0 * 64 + g * 16) ^ ((r & 7) << 4)));
      }
#pragma unroll
      for (int nfl = 0; nfl < 2; ++nfl) {
        const short8 b = *(const short8*)(wp + 196608 + (size_t)((t * 4 + K0) * 16 + w * 4 + nfl) * 512 + lane * 8);
#pragma unroll
        for (int m = 0; m < 4; ++m)
          acc[m][nfl] = __builtin_amdgcn_mfma_f32_16x16x32_bf16(a[m], b, acc[m][nfl], 0, 0, 0);
      }
    }
#pragma unroll
    for (int m = 0; m < 4; ++m)
#pragma unroll
      for (int nfl = 0; nfl < 2; ++nfl) {
        const int col = w * 64 + nfl * 16 + ar;
        const int cA = w * 32 + nfl * 16 + ar;
        const float bo = bout[t * 256 + col];
#pragma unroll
        for (int q = 0; q < 4; ++q) {
          const int r = m * 16 + g * 4 + q;
          *(short*)(Hb + r * 256 + ((cA * 2) ^ ((r & 7) << 4))) = f2bf(acc[m][nfl][q] + bo);
        }
      }
    // pass 1: cols w*64 + {32..63} -> xB into Ha (after all Ha reads done)
#pragma unroll
    for (int m = 0; m < 4; ++m) { acc[m][0] = fz; acc[m][1] = fz; }
    short8 a1[4][4];  // hoist all Ha reads of pass 1 before the barrier
#pragma unroll
    for (int K0 = 0; K0 < 4; ++K0)
#pragma unroll
      for (int m = 0; m < 4; ++m) {
        const int r = m * 16 + ar;
        a1[K0][m] = *(const short8*)(Ha + r * 256 + ((K0 * 64 + g * 16) ^ ((r & 7) << 4)));
      }
#pragma unroll
    for (int K0 = 0; K0 < 4; ++K0)
#pragma unroll
      for (int nfl = 0; nfl < 2; ++nfl) {
        const short8 b = *(const short8*)(wp + 196608 + (size_t)((t * 4 + K0) * 16 + w * 4 + 2 + nfl) * 512 + lane * 8);
#pragma unroll
        for (int m = 0; m < 4; ++m)
          acc[m][nfl] = __builtin_amdgcn_mfma_f32_16x16x32_bf16(a1[K0][m], b, acc[m][nfl], 0, 0, 0);
      }
    __syncthreads();  // all pass-1 Ha reads complete before xB overwrites Ha
#pragma unroll
    for (int m = 0; m < 4; ++m)
#pragma unroll
      for (int nfl = 0; nfl < 2; ++nfl) {
        const int col = w * 64 + 32 + nfl * 16 + ar;
        const int cB = w * 32 + nfl * 16 + ar;
        const float bo = bout[t * 256 + col];
#pragma unroll
        for (int q = 0; q < 4; ++q) {
          const int r = m * 16 + g * 4 + q;
          *(short*)(Ha + r * 256 + ((cB * 2) ^ ((r & 7) << 4))) = f2bf(acc[m][nfl][q] + bo);
        }
      }
    __syncthreads();

    // ---------- tail: 4 lanes per row; xA granules from Hb, xB from Ha ----------
    {
      const int rr = tid >> 2, qq = tid & 3;
      const int swz = (rr & 7) << 4;
      const float* kv = ti + (size_t)sUid[rr] * 256 + qq * 64;
      const float* ev = ti + (size_t)sItm[rr] * 256 + qq * 64;
      float l = 0.f, s = 0.f;
#pragma unroll
      for (int j = 0; j < 4; ++j) {
        const int off = rr * 256 + (((qq * 4 + j) * 16) ^ swz);
        const short8 xa = *(const short8*)(Hb + off);  // cols qq*64 + j*8 + [0,8)
        const short8 xb = *(const short8*)(Ha + off);  // cols qq*64 + 32 + j*8 + [0,8)
        const float4 ka0 = *(const float4*)(kv + j * 8);
        const float4 ka1 = *(const float4*)(kv + j * 8 + 4);
        const float4 kb0 = *(const float4*)(kv + 32 + j * 8);
        const float4 kb1 = *(const float4*)(kv + 32 + j * 8 + 4);
        const float4 ea0 = *(const float4*)(ev + j * 8);
        const float4 ea1 = *(const float4*)(ev + j * 8 + 4);
        const float4 eb0 = *(const float4*)(ev + 32 + j * 8);
        const float4 eb1 = *(const float4*)(ev + 32 + j * 8 + 4);
        const float a0 = bf2f(xa[0]), a1v = bf2f(xa[1]), a2 = bf2f(xa[2]), a3 = bf2f(xa[3]);
        const float a4 = bf2f(xa[4]), a5 = bf2f(xa[5]), a6 = bf2f(xa[6]), a7 = bf2f(xa[7]);
        const float b0 = bf2f(xb[0]), b1 = bf2f(xb[1]), b2 = bf2f(xb[2]), b3 = bf2f(xb[3]);
        const float b4 = bf2f(xb[4]), b5 = bf2f(xb[5]), b6 = bf2f(xb[6]), b7 = bf2f(xb[7]);
        l += a0 * ka0.x + a1v * ka0.y + a2 * ka0.z + a3 * ka0.w
           + a4 * ka1.x + a5 * ka1.y + a6 * ka1.z + a7 * ka1.w
           + b0 * kb0.x + b1 * kb0.y + b2 * kb0.z + b3 * kb0.w
           + b4 * kb1.x + b5 * kb1.y + b6 * kb1.z + b7 * kb1.w;
        s += a0 * ea0.x + a1v * ea0.y + a2 * ea0.z + a3 * ea0.w
           + a4 * ea1.x + a5 * ea1.y + a6 * ea1.z + a7 * ea1.w
           + b0 * eb0.x + b1 * eb0.y + b2 * eb0.z + b3 * eb0.w
           + b4 * eb1.x + b5 * eb1.y + b6 * eb1.z + b7 * eb1.w;
      }
      l += __shfl_xor(l, 1); l += __shfl_xor(l, 2);
      s += __shfl_xor(s, 1); s += __shfl_xor(s, 2);
      if (qq == 0) { sL[t][rr] = l; sS[t][rr] = s; }
    }
    __syncthreads();
  }

  if (tid < 64) {
    const float l0 = sL[0][tid], l1 = sL[1][tid], l2 = sL[2][tid];
    const float mx = fmaxf(l0, fmaxf(l1, l2));
    const float e0 = __expf(l0 - mx), e1 = __expf(l1 - mx), e2 = __expf(l2 - mx);
    out[blockIdx.x * 64 + tid] =
        (e0 * sS[0][tid] + e1 * sS[1][tid] + e2 * sS[2][tid]) / (e0 + e1 + e2);
  }
}

extern "C" void kernel_launch(void* const* d_in, const int* in_sizes, int n_in,
                              void* d_out, int out_size, void* d_ws, size_t ws_size,
                              hipStream_t stream) {
  const int* user = (const int*)d_in[0];
  const int* item = (const int*)d_in[1];
  const float* su = (const float*)d_in[2];
  const float* ti = (const float*)d_in[3];
  const float* Win = (const float*)d_in[4];
  const float* bin = (const float*)d_in[5];
  const float* Wh = (const float*)d_in[6];
  const float* bh = (const float*)d_in[7];
  const float* Wout = (const float*)d_in[8];
  const float* bout = (const float*)d_in[9];
  float* out = (float*)d_out;
  short* ws = (short*)d_ws;

  hipLaunchKernelGGL(pack_weights, dim3(144), dim3(256), 0, stream, Win, Wh, Wout, ws);
  hipLaunchKernelGGL(fused_towers, dim3(1024), dim3(256), 0, stream,
                     user, item, su, ti, bin, bh, bout, (const short*)ws, out);
}